// Round 12
// baseline (143.601 us; speedup 1.0000x reference)
//
#include <hip/hip_runtime.h>

// Deformable conv (K=3,N=9,PAD=1) + BN(eval) + ReLU.  B=32 C=103 H=W=32 Cout=32.
// Round 12: ping-pong double-buffered chunks, ONE barrier per chunk section.
// Tap-split compute (kh0: k-slots 0-2 / taps 0-5; kh1: slots 3-4 / taps 6-8);
// ALL staging done by kh1 (balances 3-slot kh0 vs 2-slot kh1). PLSU=1164 zeroed
// slack (r9's wrap bug fix, proven in r11). f16 pair-planes + mfma 16x16x32_f16.

#define CC    103
#define COUT  32
#define RSU   34                    // plane row stride (uints)
#define PLSU  1164                  // 34*34=1156 +8 slack; %8=4 -> quad bank offset 16
#define NPAIR 8
#define NCHUNK 7
#define BUF_U (NPAIR * PLSU)        // 9312 uints = 37248 B per buffer

typedef __attribute__((ext_vector_type(8))) _Float16 f16x8;
typedef __attribute__((ext_vector_type(2))) _Float16 h2;
typedef __attribute__((ext_vector_type(2))) __fp16  fp16x2;   // cvt_pkrtz return type
typedef __attribute__((ext_vector_type(4))) float f32x4;

// ws layout (floats): wtpm frags [0,17920), wtpo frags [17920,35840), bn [35840,35904)
#define WTPM_W 0
#define WTPO_W 17920
#define BN_W   35840

// ---------- prep: f16 weight fragments (A-layout) + BN constants ----------
// A-frag 16x16x32: lane l holds A[m=l&15][k=(l>>4)*8+j]. kl=s*32+(l>>4)*8+j;
// tap n=kl>>4; c=ch*16+(kl&15).  n>=9 / c>=103 / o>=mrows -> 0.
__global__ void k_prep(const float* __restrict__ w, const float* __restrict__ w_off,
                       const float* __restrict__ bias, const float* __restrict__ gamma,
                       const float* __restrict__ beta, const float* __restrict__ mean,
                       const float* __restrict__ var,
                       unsigned short* __restrict__ wtpm, unsigned short* __restrict__ wtpo,
                       float* __restrict__ bn) {
    int tid = blockIdx.x * 256 + threadIdx.x;
    if (tid < 71680) {
        int half_ = tid >= 35840 ? 1 : 0;
        int e = tid - half_ * 35840;
        const float* src = half_ ? w_off : w;
        unsigned short* dst = half_ ? wtpo : wtpm;
        int mrows = half_ ? 18 : 32;
        int j = e & 7, lane = (e >> 3) & 63, tile = e >> 9;
        int mt = tile & 1, chs = tile >> 1;
        int s = chs % 5, ch = chs / 5;
        int o = mt * 16 + (lane & 15);
        int kl = s * 32 + (lane >> 4) * 8 + j;
        int n = kl >> 4, c = ch * 16 + (kl & 15);
        float v = 0.f;
        if (n < 9 && c < CC && o < mrows) v = src[o * (CC * 9) + c * 9 + n];
        union { _Float16 h; unsigned short u; } cv;
        cv.h = (_Float16)v;
        dst[e] = cv.u;
    }
    if (tid < 32) {
        float inv = gamma[tid] * rsqrtf(var[tid] + 1e-5f);
        bn[tid]      = inv;
        bn[32 + tid] = beta[tid] + (bias[tid] - mean[tid]) * inv;
    }
}

// ---------- fused kernel ----------
__global__ void __launch_bounds__(512, 4)
k_fused(const float* __restrict__ x, const float* __restrict__ b_off,
        const unsigned short* __restrict__ wtpo, const unsigned short* __restrict__ wtpm,
        const float* __restrict__ bn, float* __restrict__ out) {
    __shared__ unsigned int ldsp[2 * BUF_U];
    __shared__ float exch[18 * 64];

    int bid = blockIdx.x;
    int b   = (bid & 7) * 4 + ((bid >> 3) & 3);   // XCD swizzle
    int pxg = bid >> 5;

    int t = threadIdx.x, lane = t & 63, wv = t >> 6;
    int kh = wv >> 2;                 // tap-half: 0 -> k-slots 0-2, 1 -> slots 3-4 (+staging)
    int pxl = (wv & 3) * 16 + (lane & 15);
    int px  = pxg * 64 + pxl;
    int h = px >> 5, wq = px & 31;
    int kg = lane >> 4;               // quad
    int hi2 = kg >> 1;
    int pb = (kg & 1) * 4;            // pair-plane base
    const int ns = kh ? 2 : 3;        // compute slots this half owns

    // per-lane tap tables: slot j -> global k-slot as=kh*3+j -> tap=min(2*as+hi2,8)
    int myky[3], mykx[3], mytap[3];
#pragma unroll
    for (int j = 0; j < 3; j++) {
        int as = kh * 3 + j;
        int tap = 2 * as + hi2; if (tap > 8) tap = 8;   // dup tap-8: n=9 weights zero
        mytap[j] = tap; myky[j] = tap / 3; mykx[j] = tap % 3;
    }

    const float* xb = x + b * (CC * 1024);

    // staging (kh1 threads only): thread -> (pair-plane sp, row srow), full 32-uint row
    int tq = t & 255;
    int sp = tq >> 5;                 // 0..7
    int srow = tq & 31;               // 0..31

    float4 La[8], Lb[8];
    auto loadx = [&](int ch) {
        int c = ch * 16 + 2 * sp;     // wave-uniform
        if (c < CC) {
            const float* s0 = xb + c * 1024 + srow * 32;
#pragma unroll
            for (int q = 0; q < 8; q++) La[q] = *(const float4*)(s0 + 4 * q);
            if (c + 1 < CC) {
                const float* s1 = s0 + 1024;
#pragma unroll
                for (int q = 0; q < 8; q++) Lb[q] = *(const float4*)(s1 + 4 * q);
            } else {
#pragma unroll
                for (int q = 0; q < 8; q++) Lb[q] = make_float4(0.f, 0.f, 0.f, 0.f);
            }
        }
    };
    auto packwrite = [&](int ch, int bufi) {
        int c = ch * 16 + 2 * sp;
        if (c >= CC) return;          // stale planes stay finite; weights are zero
        unsigned int* dst = ldsp + bufi * BUF_U + sp * PLSU + (srow + 1) * RSU + 2;
#pragma unroll
        for (int q = 0; q < 8; q++) {
            union { fp16x2 hh; unsigned u; } p0, p1, p2, p3;
            p0.hh = __builtin_amdgcn_cvt_pkrtz(La[q].x, Lb[q].x);
            p1.hh = __builtin_amdgcn_cvt_pkrtz(La[q].y, Lb[q].y);
            p2.hh = __builtin_amdgcn_cvt_pkrtz(La[q].z, Lb[q].z);
            p3.hh = __builtin_amdgcn_cvt_pkrtz(La[q].w, Lb[q].w);
            *(uint2*)(dst + 4 * q)     = make_uint2(p0.u, p1.u);
            *(uint2*)(dst + 4 * q + 2) = make_uint2(p2.u, p3.u);
        }
    };

    f32x4 acc0 = {0.f, 0.f, 0.f, 0.f};
    f32x4 acc1 = {0.f, 0.f, 0.f, 0.f};

    // prologue: zero both buffers (pad ring + slack); kh1 stages chunk 0 -> buf0
    for (int i = t; i < 2 * BUF_U; i += 512) ldsp[i] = 0u;
    __syncthreads();
    if (kh == 1) { loadx(0); packwrite(0, 0); }
    __syncthreads();

    // ================= phase 1: offset conv (ping-pong, 1 barrier/section) ==========
    for (int it = 0; it < NCHUNK; it++) {
        if (kh == 1 && it < 6) loadx(it + 1);
        {
            const unsigned int* bufp = ldsp + (it & 1) * BUF_U;
            const unsigned short* wch = wtpo + it * 5120;
#pragma unroll
            for (int j = 0; j < 3; j++) {
                if (j < ns) {
                    int as = kh * 3 + j;
                    const unsigned int* cell = bufp + pb * PLSU
                        + (h + myky[j]) * RSU + 1 + (wq + mykx[j]);
                    union { unsigned u[4]; f16x8 v; } bu;
#pragma unroll
                    for (int jj = 0; jj < 4; jj++) bu.u[jj] = cell[jj * PLSU];
                    f16x8 a0 = *(const f16x8*)(wch + as * 1024 + lane * 8);
                    f16x8 a1 = *(const f16x8*)(wch + as * 1024 + 512 + lane * 8);
                    acc0 = __builtin_amdgcn_mfma_f32_16x16x32_f16(a0, bu.v, acc0, 0, 0, 0);
                    acc1 = __builtin_amdgcn_mfma_f32_16x16x32_f16(a1, bu.v, acc1, 0, 0, 0);
                }
            }
        }
        if (kh == 1 && it < 6) packwrite(it + 1, (it + 1) & 1);
        __syncthreads();
    }

    // ---- reduce offset partials across tap-halves (C-layout: row=kg*4+reg, col=pxl)
    if (kh == 0) {
        float* ex = exch + pxl;
#pragma unroll
        for (int reg = 0; reg < 4; reg++) ex[(kg * 4 + reg) * 64] = acc0[reg];
        if (kg == 0) { ex[16 * 64] = acc1[0]; ex[17 * 64] = acc1[1]; }
    }
    __syncthreads();
    if (kh == 1) {
        float* ex = exch + pxl;
#pragma unroll
        for (int reg = 0; reg < 4; reg++) ex[(kg * 4 + reg) * 64] += acc0[reg];
        if (kg == 0) { ex[16 * 64] += acc1[0]; ex[17 * 64] += acc1[1]; }
    }
    __syncthreads();

    // ---- geometry (ns slots per lane). Buffers hold ch6 (buf0), ch5 (buf1).
    int cofs[3];
    h2  W[3][4];
#pragma unroll
    for (int j = 0; j < 3; j++) {
        int tap = mytap[j];
        float oy = exch[tap * 64 + pxl] + b_off[tap];
        float ox = exch[(9 + tap) * 64 + pxl] + b_off[9 + tap];
        float py  = (float)(h + myky[j]) + oy;    // padded coords
        float pxx = (float)(wq + mykx[j]) + ox;
        py  = fminf(fmaxf(py, 0.f), 33.f);
        pxx = fminf(fmaxf(pxx, 0.f), 33.f);
        int y0 = min((int)py, 32);
        int x0 = min((int)pxx, 32);
        float fy = py - (float)y0;
        float fx = pxx - (float)x0;
        float w00 = (1.f - fy) * (1.f - fx), w01 = (1.f - fy) * fx;
        float w10 = fy * (1.f - fx),          w11 = fy * fx;
        W[j][0] = (h2){(_Float16)w00, (_Float16)w00};
        W[j][1] = (h2){(_Float16)w01, (_Float16)w01};
        W[j][2] = (h2){(_Float16)w10, (_Float16)w10};
        W[j][3] = (h2){(_Float16)w11, (_Float16)w11};
        cofs[j] = pb * PLSU + y0 * RSU + 1 + x0;
        // col index can reach 34 -> wraps to next row col 0 (zero) or, plane 7,
        // the zeroed PLSU slack. True sample there is pad=0. Safe (r9 bug fix).
    }

    // ================= phase 2: deformable conv (chunks 6..0; 6,5 resident) =========
    acc0 = (f32x4){0.f, 0.f, 0.f, 0.f};
    acc1 = (f32x4){0.f, 0.f, 0.f, 0.f};
    for (int jt = 0; jt < NCHUNK; jt++) {
        int ch = 6 - jt;                          // section jt reads buf[jt&1]
        if (kh == 1 && jt >= 1 && jt <= 5) loadx(5 - jt);
        {
            const unsigned int* bufp = ldsp + (jt & 1) * BUF_U;
            const unsigned short* wch = wtpm + ch * 5120;
#pragma unroll
            for (int j = 0; j < 3; j++) {
                if (j < ns) {
                    int as = kh * 3 + j;
                    const unsigned int* cell = bufp + cofs[j];
                    union { unsigned u[4]; f16x8 v; } bu;
#pragma unroll
                    for (int jj = 0; jj < 4; jj++) {
                        union { unsigned u; h2 hh; } t0, t1, b0, b1;
                        t0.u = cell[jj * PLSU];
                        t1.u = cell[jj * PLSU + 1];
                        b0.u = cell[jj * PLSU + RSU];
                        b1.u = cell[jj * PLSU + RSU + 1];
                        h2 sm = t0.hh * W[j][0] + t1.hh * W[j][1]
                              + b0.hh * W[j][2] + b1.hh * W[j][3];
                        union { h2 hh; unsigned u; } r; r.hh = sm;
                        bu.u[jj] = r.u;
                    }
                    f16x8 a0 = *(const f16x8*)(wch + as * 1024 + lane * 8);
                    f16x8 a1 = *(const f16x8*)(wch + as * 1024 + 512 + lane * 8);
                    acc0 = __builtin_amdgcn_mfma_f32_16x16x32_f16(a0, bu.v, acc0, 0, 0, 0);
                    acc1 = __builtin_amdgcn_mfma_f32_16x16x32_f16(a1, bu.v, acc1, 0, 0, 0);
                }
            }
        }
        if (kh == 1 && jt >= 1 && jt <= 5) packwrite(5 - jt, (jt + 1) & 1);
        __syncthreads();
    }

    // ---- final reduce (overlay on dead buf0) + BN + ReLU + store
    float* ex2 = (float*)ldsp;
    if (kh == 0) {
        float* e = ex2 + pxl;
#pragma unroll
        for (int reg = 0; reg < 4; reg++) {
            e[(kg * 4 + reg) * 64]      = acc0[reg];
            e[(16 + kg * 4 + reg) * 64] = acc1[reg];
        }
    }
    __syncthreads();
    if (kh == 1) {
        float* op = out + (size_t)b * COUT * 1024 + px;
#pragma unroll
        for (int mt = 0; mt < 2; mt++) {
            f32x4 a = mt ? acc1 : acc0;
#pragma unroll
            for (int reg = 0; reg < 4; reg++) {
                int o = mt * 16 + kg * 4 + reg;
                float tot = a[reg] + ex2[o * 64 + pxl];
                float v = tot * bn[o] + bn[32 + o];
                op[o * 1024] = fmaxf(v, 0.f);
            }
        }
    }
}

extern "C" void kernel_launch(void* const* d_in, const int* in_sizes, int n_in,
                              void* d_out, int out_size, void* d_ws, size_t ws_size,
                              hipStream_t stream) {
    const float* x      = (const float*)d_in[0];
    const float* w_off  = (const float*)d_in[1];
    const float* b_off  = (const float*)d_in[2];
    const float* w      = (const float*)d_in[3];
    const float* bias   = (const float*)d_in[4];
    const float* gamma  = (const float*)d_in[5];
    const float* beta   = (const float*)d_in[6];
    const float* rmean  = (const float*)d_in[7];
    const float* rvar   = (const float*)d_in[8];
    float* out = (float*)d_out;

    float* ws = (float*)d_ws;
    unsigned short* wtpm = (unsigned short*)(ws + WTPM_W);
    unsigned short* wtpo = (unsigned short*)(ws + WTPO_W);
    float*          bn   = ws + BN_W;

    k_prep <<<280, 256, 0, stream>>>(w, w_off, bias, gamma, beta, rmean, rvar,
                                     wtpm, wtpo, bn);
    k_fused<<<512, 512, 0, stream>>>(x, b_off, wtpo, wtpm, bn, out);
}

// Round 13
// 108.543 us; speedup vs baseline: 1.3230x; 1.3230x over previous
//
#include <hip/hip_runtime.h>

// Deformable conv (K=3,N=9,PAD=1) + BN(eval) + ReLU.  B=32 C=103 H=W=32 Cout=32.
// Round 13: r10 known-good dataflow (chunk-split K across two 4-wave halves,
// private per-half buffers, 2 barriers/chunk, 5 slots/wave/section) + A-fragment
// register prefetch: all 10 global frag loads issue BEFORE staging, drain under
// the staging/barrier, compute reads registers. Merged stage (no L/M prefetch).

#define CC    103
#define COUT  32
#define KSC   5            // k-steps (K=32) per 16-channel chunk
#define RSU   34           // plane row stride (uints)
#define PLSU  1164         // 34*34=1156 +8 slack; %8=4 -> pb-quad bank offset 16
#define NPAIR 8
#define BUF_U (NPAIR * PLSU)        // 9312 uints = 37248 B per half-buffer

typedef __attribute__((ext_vector_type(8))) _Float16 f16x8;
typedef __attribute__((ext_vector_type(2))) _Float16 h2;
typedef __attribute__((ext_vector_type(2))) __fp16  fp16x2;   // cvt_pkrtz return type
typedef __attribute__((ext_vector_type(4))) float f32x4;

// ws layout (floats): wtpm frags [0,17920), wtpo frags [17920,35840), bn [35840,35904)
#define WTPM_W 0
#define WTPO_W 17920
#define BN_W   35840

// ---------- prep: f16 weight fragments (A-layout) + BN constants ----------
// A-frag 16x16x32: lane l holds A[m=l&15][k=(l>>4)*8+j]. kl=s*32+(l>>4)*8+j;
// tap n=kl>>4; c=ch*16+(kl&15).  n>=9 / c>=103 / o>=mrows -> 0.
__global__ void k_prep(const float* __restrict__ w, const float* __restrict__ w_off,
                       const float* __restrict__ bias, const float* __restrict__ gamma,
                       const float* __restrict__ beta, const float* __restrict__ mean,
                       const float* __restrict__ var,
                       unsigned short* __restrict__ wtpm, unsigned short* __restrict__ wtpo,
                       float* __restrict__ bn) {
    int tid = blockIdx.x * 256 + threadIdx.x;
    if (tid < 71680) {
        int half_ = tid >= 35840 ? 1 : 0;
        int e = tid - half_ * 35840;
        const float* src = half_ ? w_off : w;
        unsigned short* dst = half_ ? wtpo : wtpm;
        int mrows = half_ ? 18 : 32;
        int j = e & 7, lane = (e >> 3) & 63, tile = e >> 9;
        int mt = tile & 1, chs = tile >> 1;
        int s = chs % 5, ch = chs / 5;
        int o = mt * 16 + (lane & 15);
        int kl = s * 32 + (lane >> 4) * 8 + j;
        int n = kl >> 4, c = ch * 16 + (kl & 15);
        float v = 0.f;
        if (n < 9 && c < CC && o < mrows) v = src[o * (CC * 9) + c * 9 + n];
        union { _Float16 h; unsigned short u; } cv;
        cv.h = (_Float16)v;
        dst[e] = cv.u;
    }
    if (tid < 32) {
        float inv = gamma[tid] * rsqrtf(var[tid] + 1e-5f);
        bn[tid]      = inv;
        bn[32 + tid] = beta[tid] + (bias[tid] - mean[tid]) * inv;
    }
}

// ---------- fused kernel ----------
__global__ void __launch_bounds__(512, 4)
k_fused(const float* __restrict__ x, const float* __restrict__ b_off,
        const unsigned short* __restrict__ wtpo, const unsigned short* __restrict__ wtpm,
        const float* __restrict__ bn, float* __restrict__ out) {
    __shared__ unsigned int ldsp[2 * BUF_U];
    __shared__ float exch[18 * 64];

    int bid = blockIdx.x;
    int b   = (bid & 7) * 4 + ((bid >> 3) & 3);   // XCD swizzle
    int pxg = bid >> 5;

    int t = threadIdx.x, lane = t & 63, wv = t >> 6;
    int kh = wv >> 2;                 // chunk-half: 0 -> chunks {1,3,5}, 1 -> {0,2,4,6}
    int pxl = (wv & 3) * 16 + (lane & 15);
    int px  = pxg * 64 + pxl;
    int h = px >> 5, wq = px & 31;
    int kg = lane >> 4;               // quad
    int hi = kg >> 1;
    int pb = (kg & 1) * 4;            // pair-plane base

    unsigned int* mybuf = ldsp + kh * BUF_U;

    const float* xb = x + b * (CC * 1024);
    int tl = t & 255;
    int sr = tl >> 3, sc = (tl & 7) * 4;          // staging row / col group

    // per-lane tap tables (lo-quads taps 0,2,4,6,8; hi-quads 1,3,5,7,8; tap8 dup = zero wt)
    const int KYL[5] = {0,0,1,2,2}, KXL[5] = {0,2,1,0,2};
    const int KYH[5] = {0,1,1,2,2}, KXH[5] = {1,0,2,1,2};
    const int TAPL[5] = {0,2,4,6,8}, TAPH[5] = {1,3,5,7,8};
    int myky[5], mykx[5], mytap[5];
#pragma unroll
    for (int s = 0; s < 5; s++) {
        myky[s] = hi ? KYH[s] : KYL[s];
        mykx[s] = hi ? KXH[s] : KXL[s];
        mytap[s] = hi ? TAPH[s] : TAPL[s];
    }

    // merged stage: load + pack + LDS write (16 loads in flight per thread)
    auto stage = [&](int ch) {
        const float* s0 = xb + sr * 32 + sc;
        unsigned int* dstb = mybuf + (sr + 1) * RSU + 2 + sc;
#pragma unroll
        for (int i = 0; i < NPAIR; i++) {
            int c = ch * 16 + 2 * i;              // uniform per i
            if (c < CC) {
                float4 a = *(const float4*)(s0 + c * 1024);
                float4 m = (c + 1 < CC) ? *(const float4*)(s0 + (c + 1) * 1024)
                                        : make_float4(0.f, 0.f, 0.f, 0.f);
                union { fp16x2 hh; unsigned u; } p0, p1, p2, p3;
                p0.hh = __builtin_amdgcn_cvt_pkrtz(a.x, m.x);
                p1.hh = __builtin_amdgcn_cvt_pkrtz(a.y, m.y);
                p2.hh = __builtin_amdgcn_cvt_pkrtz(a.z, m.z);
                p3.hh = __builtin_amdgcn_cvt_pkrtz(a.w, m.w);
                *(uint2*)(dstb + i * PLSU)     = make_uint2(p0.u, p1.u);
                *(uint2*)(dstb + i * PLSU + 2) = make_uint2(p2.u, p3.u);
            }                                     // c>=103: stale-but-finite, zero weights
        }
    };

    // A-frag prefetch: 10 x b128 issued together (drain under staging/barrier)
    auto loadfrags = [&](const unsigned short* wch, f16x8* fr) {
#pragma unroll
        for (int s = 0; s < KSC; s++) {
            fr[2 * s]     = *(const f16x8*)(wch + s * 1024 + lane * 8);
            fr[2 * s + 1] = *(const f16x8*)(wch + s * 1024 + 512 + lane * 8);
        }
    };

    auto chunk1 = [&](int it) { return kh ? (2 * it) : (it < 3 ? 2 * it + 1 : -1); };
    auto chunk2 = [&](int it) { return kh ? (6 - 2 * it) : (it < 3 ? 5 - 2 * it : -1); };

    f32x4 acc0 = {0.f, 0.f, 0.f, 0.f};
    f32x4 acc1 = {0.f, 0.f, 0.f, 0.f};

    // prologue: zero both buffers (pad ring + slack)
    for (int i = t; i < 2 * BUF_U; i += 512) ldsp[i] = 0u;
    __syncthreads();

    // ================= phase 1: offset conv =================
#pragma unroll
    for (int it = 0; it < 4; it++) {
        int ch = chunk1(it);
        f16x8 fr[10];
        if (ch >= 0) {
            loadfrags(wtpo + ch * 5120, fr);      // issue first: hides under staging
            stage(ch);
        }
        __syncthreads();                          // staging visible
        if (ch >= 0) {
#pragma unroll
            for (int s = 0; s < KSC; s++) {
                const unsigned int* cell = mybuf + pb * PLSU
                    + (h + myky[s]) * RSU + 1 + (wq + mykx[s]);
                union { unsigned u[4]; f16x8 v; } bu;
#pragma unroll
                for (int jj = 0; jj < 4; jj++) bu.u[jj] = cell[jj * PLSU];
                acc0 = __builtin_amdgcn_mfma_f32_16x16x32_f16(fr[2*s],   bu.v, acc0, 0, 0, 0);
                acc1 = __builtin_amdgcn_mfma_f32_16x16x32_f16(fr[2*s+1], bu.v, acc1, 0, 0, 0);
            }
        }
        __syncthreads();                          // compute drained before next overwrite
    }

    // ---- reduce offset partials across halves (C-layout: row=kg*4+reg, col=pxl)
    if (kh == 0) {
        float* ex = exch + pxl;
#pragma unroll
        for (int reg = 0; reg < 4; reg++) ex[(kg * 4 + reg) * 64] = acc0[reg];
        if (kg == 0) { ex[16 * 64] = acc1[0]; ex[17 * 64] = acc1[1]; }
    }
    __syncthreads();
    if (kh == 1) {
        float* ex = exch + pxl;
#pragma unroll
        for (int reg = 0; reg < 4; reg++) ex[(kg * 4 + reg) * 64] += acc0[reg];
        if (kg == 0) { ex[16 * 64] += acc1[0]; ex[17 * 64] += acc1[1]; }
    }
    __syncthreads();

    // ---- geometry (once; 5 slots per lane)
    int cofs[KSC];
    h2  W[KSC][4];
#pragma unroll
    for (int s = 0; s < KSC; s++) {
        int tap = mytap[s];
        float oy = exch[tap * 64 + pxl] + b_off[tap];
        float ox = exch[(9 + tap) * 64 + pxl] + b_off[9 + tap];
        float py  = (float)(h + myky[s]) + oy;    // padded coords
        float pxx = (float)(wq + mykx[s]) + ox;
        py  = fminf(fmaxf(py, 0.f), 33.f);
        pxx = fminf(fmaxf(pxx, 0.f), 33.f);
        int y0 = min((int)py, 32);
        int x0 = min((int)pxx, 32);
        float fy = py - (float)y0;
        float fx = pxx - (float)x0;
        float w00 = (1.f - fy) * (1.f - fx), w01 = (1.f - fy) * fx;
        float w10 = fy * (1.f - fx),          w11 = fy * fx;
        W[s][0] = (h2){(_Float16)w00, (_Float16)w00};
        W[s][1] = (h2){(_Float16)w01, (_Float16)w01};
        W[s][2] = (h2){(_Float16)w10, (_Float16)w10};
        W[s][3] = (h2){(_Float16)w11, (_Float16)w11};
        cofs[s] = pb * PLSU + y0 * RSU + 1 + x0;
        // col index can reach 34 -> wraps to next row col 0 (zero) or, plane 7,
        // the zeroed PLSU slack. True sample there is pad=0. Safe.
    }

    // ================= phase 2: deformable conv (chunks reversed; first resident) ====
    acc0 = (f32x4){0.f, 0.f, 0.f, 0.f};
    acc1 = (f32x4){0.f, 0.f, 0.f, 0.f};
#pragma unroll
    for (int it = 0; it < 4; it++) {
        int ch = chunk2(it);
        f16x8 fr[10];
        if (ch >= 0) loadfrags(wtpm + ch * 5120, fr);
        if (it > 0) {
            if (ch >= 0) stage(ch);
            else {  // kh==0, it==3: publish main partials into kh0's dead buffer
                float* e = (float*)ldsp + pxl;
#pragma unroll
                for (int reg = 0; reg < 4; reg++) {
                    e[(kg * 4 + reg) * 64]      = acc0[reg];
                    e[(16 + kg * 4 + reg) * 64] = acc1[reg];
                }
            }
        }
        __syncthreads();
        if (ch >= 0) {
#pragma unroll
            for (int s = 0; s < KSC; s++) {
                const unsigned int* cell = mybuf + cofs[s];
                union { unsigned u[4]; f16x8 v; } bu;
#pragma unroll
                for (int jj = 0; jj < 4; jj++) {
                    union { unsigned u; h2 hh; } t0, t1, b0, b1;
                    t0.u = cell[jj * PLSU];
                    t1.u = cell[jj * PLSU + 1];
                    b0.u = cell[jj * PLSU + RSU];
                    b1.u = cell[jj * PLSU + RSU + 1];
                    h2 sm = t0.hh * W[s][0] + t1.hh * W[s][1]
                          + b0.hh * W[s][2] + b1.hh * W[s][3];
                    union { h2 hh; unsigned u; } r; r.hh = sm;
                    bu.u[jj] = r.u;
                }
                acc0 = __builtin_amdgcn_mfma_f32_16x16x32_f16(fr[2*s],   bu.v, acc0, 0, 0, 0);
                acc1 = __builtin_amdgcn_mfma_f32_16x16x32_f16(fr[2*s+1], bu.v, acc1, 0, 0, 0);
            }
        }
        __syncthreads();
    }

    // ---- final reduce + BN + ReLU + store (kh1 adds kh0's published partials)
    if (kh == 1) {
        const float* ex2 = (const float*)ldsp;
        float* op = out + (size_t)b * COUT * 1024 + px;
#pragma unroll
        for (int mt = 0; mt < 2; mt++) {
            f32x4 a = mt ? acc1 : acc0;
#pragma unroll
            for (int reg = 0; reg < 4; reg++) {
                int o = mt * 16 + kg * 4 + reg;
                float tot = a[reg] + ex2[o * 64 + pxl];
                float v = tot * bn[o] + bn[32 + o];
                op[o * 1024] = fmaxf(v, 0.f);
            }
        }
    }
}

extern "C" void kernel_launch(void* const* d_in, const int* in_sizes, int n_in,
                              void* d_out, int out_size, void* d_ws, size_t ws_size,
                              hipStream_t stream) {
    const float* x      = (const float*)d_in[0];
    const float* w_off  = (const float*)d_in[1];
    const float* b_off  = (const float*)d_in[2];
    const float* w      = (const float*)d_in[3];
    const float* bias   = (const float*)d_in[4];
    const float* gamma  = (const float*)d_in[5];
    const float* beta   = (const float*)d_in[6];
    const float* rmean  = (const float*)d_in[7];
    const float* rvar   = (const float*)d_in[8];
    float* out = (float*)d_out;

    float* ws = (float*)d_ws;
    unsigned short* wtpm = (unsigned short*)(ws + WTPM_W);
    unsigned short* wtpo = (unsigned short*)(ws + WTPO_W);
    float*          bn   = ws + BN_W;

    k_prep <<<280, 256, 0, stream>>>(w, w_off, bias, gamma, beta, rmean, rvar,
                                     wtpm, wtpo, bn);
    k_fused<<<512, 512, 0, stream>>>(x, b_off, wtpo, wtpm, bn, out);
}